// Round 1
// baseline (2516.143 us; speedup 1.0000x reference)
//
#include <hip/hip_runtime.h>
#include <math.h>

#define EMBED 768
#define NHEADS 12
#define HDIM 64
#define SEQ 1025
#define NBATCH 8
#define BHCOUNT (NBATCH*NHEADS)   // 96
#define MROWS (NBATCH*SEQ)        // 8200
#define QKV_N (3*EMBED)           // 2304
#define SCALE 0.125f
#define QKV_ELEMS (BHCOUNT*SEQ*HDIM)  // 6,297,600 floats per tensor

// ---------------- RoPE tables: cos/sin [1024][64] ----------------
__global__ void rope_table_kernel(float* __restrict__ cosT, float* __restrict__ sinT) {
    int s = blockIdx.x;        // image token index 0..1023
    int d = threadIdx.x;       // 0..63
    int pos = (d < 32) ? (s >> 5) : (s & 31);   // row for first half, col for second
    int j = (d & 31) >> 1;                      // freq index 0..15
    // inv_freq[j] = 10000^(-j/16)  -> exp(-j * ln(10000)/16)
    float ang = (float)pos * expf(-(float)j * 0.5756462732485115f);
    cosT[(s << 6) + d] = cosf(ang);
    sinT[(s << 6) + d] = sinf(ang);
}

// ---------------- QKV GEMM: out = x @ qkv_w^T + b, fused RoPE + scatter ----------------
// x: [8200, 768], qkv_w: [2304, 768] (NT gemm, both K-contiguous)
// writes q (pre-scaled by SCALE), k, v as [B, H, S, D]
__global__ __launch_bounds__(256)
void qkv_gemm_kernel(const float* __restrict__ x, const float* __restrict__ w,
                     const float* __restrict__ bias,
                     const float* __restrict__ cosT, const float* __restrict__ sinT,
                     float* __restrict__ qout, float* __restrict__ kout,
                     float* __restrict__ vout)
{
    __shared__ float As[16][68];   // [k][m], pad 68 keeps float4 aligned, <=2-way banks
    __shared__ float Bs[16][68];   // [k][n]
    const int m0 = blockIdx.x * 64;
    const int n0 = blockIdx.y * 64;
    const int tid = threadIdx.x;
    const int tm = tid >> 4, tn = tid & 15;
    const int lr = tid >> 2, lc = (tid & 3) << 2;

    float acc[4][4] = {};
    const float* aptr = x + (long)(m0 + lr) * EMBED + lc;
    const float* bptr = w + (long)(n0 + lr) * EMBED + lc;
    const bool avalid = (m0 + lr) < MROWS;

    for (int k0 = 0; k0 < EMBED; k0 += 16) {
        float4 av = make_float4(0.f, 0.f, 0.f, 0.f);
        if (avalid) av = *reinterpret_cast<const float4*>(aptr + k0);
        float4 bv = *reinterpret_cast<const float4*>(bptr + k0);
        As[lc + 0][lr] = av.x; As[lc + 1][lr] = av.y;
        As[lc + 2][lr] = av.z; As[lc + 3][lr] = av.w;
        Bs[lc + 0][lr] = bv.x; Bs[lc + 1][lr] = bv.y;
        Bs[lc + 2][lr] = bv.z; Bs[lc + 3][lr] = bv.w;
        __syncthreads();
        #pragma unroll
        for (int kk = 0; kk < 16; ++kk) {
            const float4 a4 = *reinterpret_cast<const float4*>(&As[kk][tm << 2]);
            const float4 b4 = *reinterpret_cast<const float4*>(&Bs[kk][tn << 2]);
            const float a[4] = {a4.x, a4.y, a4.z, a4.w};
            const float b[4] = {b4.x, b4.y, b4.z, b4.w};
            #pragma unroll
            for (int i = 0; i < 4; ++i)
                #pragma unroll
                for (int j = 0; j < 4; ++j)
                    acc[i][j] += a[i] * b[j];
        }
        __syncthreads();
    }

    const int nbase = n0 + (tn << 2);        // 4 consecutive n, 16-aligned blocks
    const int which = nbase / EMBED;         // 0=q 1=k 2=v (uniform over the 4)
    const int h = (nbase >> 6) % NHEADS;
    const int d0 = nbase & 63;               // even, rope pairs stay in-thread
    float* outp = (which == 0) ? qout : (which == 1) ? kout : vout;
    const float mul = (which == 0) ? SCALE : 1.0f;
    const float b0 = bias[nbase + 0], b1 = bias[nbase + 1];
    const float b2 = bias[nbase + 2], b3 = bias[nbase + 3];

    #pragma unroll
    for (int i = 0; i < 4; ++i) {
        int m = m0 + (tm << 2) + i;
        if (m >= MROWS) break;
        int bb = m / SEQ, s = m - bb * SEQ;
        float v0 = acc[i][0] + b0, v1 = acc[i][1] + b1;
        float v2 = acc[i][2] + b2, v3 = acc[i][3] + b3;
        if (which < 2 && s >= 1) {           // RoPE on q,k image tokens
            int p = s - 1;
            const float* ct = cosT + (p << 6) + d0;
            const float* st = sinT + (p << 6) + d0;
            float c0 = ct[0], s0 = st[0], c2 = ct[2], s2 = st[2];
            float e = v0, o = v1;
            v0 = e * c0 - o * s0; v1 = o * c0 + e * s0;
            e = v2; o = v3;
            v2 = e * c2 - o * s2; v3 = o * c2 + e * s2;
        }
        float4 res = make_float4(v0 * mul, v1 * mul, v2 * mul, v3 * mul);
        *reinterpret_cast<float4*>(
            &outp[((long)bb * NHEADS + h) * (SEQ * HDIM) + (long)s * HDIM + d0]) = res;
    }
}

// ---------------- Flash attention with rel-pos bias ----------------
// grid: (17 q-tiles, 96 b*h). block 256. q/k/v: [B,H,S,D]; q pre-scaled.
__global__ __launch_bounds__(256)
void attn_kernel(const float* __restrict__ qg, const float* __restrict__ kg,
                 const float* __restrict__ vg, const float* __restrict__ bt,
                 const unsigned char* __restrict__ mask, float* __restrict__ ctx)
{
    __shared__ float Qs[64][68];
    __shared__ float KPs[64][68];   // K-tile, then reused for P-tile
    __shared__ float Vs[64][68];

    const int q0 = blockIdx.x * 64;
    const int bh = (int)blockIdx.y;
    const int b = bh / NHEADS, h = bh % NHEADS;
    const int tid = threadIdx.x;
    const int tq = tid >> 4;   // q-row group 0..15
    const int tx = tid & 15;   // k-col / d-col group 0..15

    const float* qbase = qg + (long)bh * (SEQ * HDIM);
    const float* kbase = kg + (long)bh * (SEQ * HDIM);
    const float* vbase = vg + (long)bh * (SEQ * HDIM);

    for (int i = tid; i < 64 * 16; i += 256) {
        int r = i >> 4, c = (i & 15) << 2;
        int qi = q0 + r;
        float4 val = make_float4(0.f, 0.f, 0.f, 0.f);
        if (qi < SEQ) val = *reinterpret_cast<const float4*>(&qbase[qi * HDIM + c]);
        *reinterpret_cast<float4*>(&Qs[r][c]) = val;
    }

    float m_r[4], l_r[4], o_r[4][4];
    #pragma unroll
    for (int i = 0; i < 4; ++i) {
        m_r[i] = -1e30f; l_r[i] = 0.f;
        #pragma unroll
        for (int j = 0; j < 4; ++j) o_r[i][j] = 0.f;
    }

    for (int kt = 0; kt < 17; ++kt) {
        const int k0 = kt * 64;
        __syncthreads();  // previous PV done before overwriting KPs/Vs (also covers Q load)
        for (int i = tid; i < 64 * 16; i += 256) {
            int r = i >> 4, c = (i & 15) << 2;
            int ki = k0 + r;
            float4 kv = make_float4(0.f, 0.f, 0.f, 0.f);
            float4 vv = make_float4(0.f, 0.f, 0.f, 0.f);
            if (ki < SEQ) {
                kv = *reinterpret_cast<const float4*>(&kbase[ki * HDIM + c]);
                vv = *reinterpret_cast<const float4*>(&vbase[ki * HDIM + c]);
            }
            *reinterpret_cast<float4*>(&KPs[r][c]) = kv;
            *reinterpret_cast<float4*>(&Vs[r][c]) = vv;
        }
        __syncthreads();

        // scores: q rows tq*4+ii, k cols tx+16*jj (strided -> 2-way LDS banks)
        float sc[4][4] = {};
        #pragma unroll
        for (int d0 = 0; d0 < 64; d0 += 4) {
            float4 qa[4], kb[4];
            #pragma unroll
            for (int ii = 0; ii < 4; ++ii)
                qa[ii] = *reinterpret_cast<const float4*>(&Qs[(tq << 2) + ii][d0]);
            #pragma unroll
            for (int jj = 0; jj < 4; ++jj)
                kb[jj] = *reinterpret_cast<const float4*>(&KPs[tx + (jj << 4)][d0]);
            #pragma unroll
            for (int ii = 0; ii < 4; ++ii)
                #pragma unroll
                for (int jj = 0; jj < 4; ++jj)
                    sc[ii][jj] += qa[ii].x * kb[jj].x + qa[ii].y * kb[jj].y +
                                  qa[ii].z * kb[jj].z + qa[ii].w * kb[jj].w;
        }

        // bias + padding mask + bounds
        #pragma unroll
        for (int ii = 0; ii < 4; ++ii) {
            int qi = q0 + (tq << 2) + ii;
            #pragma unroll
            for (int jj = 0; jj < 4; ++jj) {
                int ki = k0 + tx + (jj << 4);
                float s = sc[ii][jj];
                if (ki >= SEQ || qi >= SEQ) {
                    s = -1e30f;    // finite: avoids inf-inf NaN in dead rows
                } else {
                    if (qi >= 1 && ki >= 1) {
                        int qp = qi - 1, kp = ki - 1;
                        int idx = ((qp >> 5) - (kp >> 5) + 31) * 63 +
                                  ((qp & 31) - (kp & 31) + 31);
                        s += bt[idx * NHEADS + h];
                    }
                    if (mask[b * SEQ + ki]) s = -1e30f;
                }
                sc[ii][jj] = s;
            }
        }

        // online softmax (row reduction across the 16-lane tx group)
        float alpha[4];
        #pragma unroll
        for (int ii = 0; ii < 4; ++ii) {
            float mx = fmaxf(fmaxf(sc[ii][0], sc[ii][1]), fmaxf(sc[ii][2], sc[ii][3]));
            #pragma unroll
            for (int off = 1; off < 16; off <<= 1)
                mx = fmaxf(mx, __shfl_xor(mx, off, 64));
            float mnew = fmaxf(m_r[ii], mx);
            alpha[ii] = expf(m_r[ii] - mnew);
            float rs = 0.f;
            #pragma unroll
            for (int jj = 0; jj < 4; ++jj) {
                float p = expf(sc[ii][jj] - mnew);
                sc[ii][jj] = p;
                rs += p;
            }
            #pragma unroll
            for (int off = 1; off < 16; off <<= 1)
                rs += __shfl_xor(rs, off, 64);
            l_r[ii] = l_r[ii] * alpha[ii] + rs;
            m_r[ii] = mnew;
        }

        __syncthreads();           // all scores read from KPs before overwrite with P
        #pragma unroll
        for (int ii = 0; ii < 4; ++ii)
            #pragma unroll
            for (int jj = 0; jj < 4; ++jj)
                KPs[(tq << 2) + ii][tx + (jj << 4)] = sc[ii][jj];
        __syncthreads();

        // PV: o rows tq*4+ii, d cols tx*4+jj
        #pragma unroll
        for (int ii = 0; ii < 4; ++ii)
            #pragma unroll
            for (int jj = 0; jj < 4; ++jj)
                o_r[ii][jj] *= alpha[ii];
        #pragma unroll
        for (int kk0 = 0; kk0 < 64; kk0 += 4) {
            float4 pa[4], vb[4];
            #pragma unroll
            for (int ii = 0; ii < 4; ++ii)
                pa[ii] = *reinterpret_cast<const float4*>(&KPs[(tq << 2) + ii][kk0]);
            #pragma unroll
            for (int t = 0; t < 4; ++t)
                vb[t] = *reinterpret_cast<const float4*>(&Vs[kk0 + t][tx << 2]);
            #pragma unroll
            for (int ii = 0; ii < 4; ++ii) {
                o_r[ii][0] += pa[ii].x * vb[0].x + pa[ii].y * vb[1].x +
                              pa[ii].z * vb[2].x + pa[ii].w * vb[3].x;
                o_r[ii][1] += pa[ii].x * vb[0].y + pa[ii].y * vb[1].y +
                              pa[ii].z * vb[2].y + pa[ii].w * vb[3].y;
                o_r[ii][2] += pa[ii].x * vb[0].z + pa[ii].y * vb[1].z +
                              pa[ii].z * vb[2].z + pa[ii].w * vb[3].z;
                o_r[ii][3] += pa[ii].x * vb[0].w + pa[ii].y * vb[1].w +
                              pa[ii].z * vb[2].w + pa[ii].w * vb[3].w;
            }
        }
    }

    // epilogue: ctx[b, s, h*64 + d]
    #pragma unroll
    for (int ii = 0; ii < 4; ++ii) {
        int qi = q0 + (tq << 2) + ii;
        if (qi < SEQ) {
            float inv = 1.0f / l_r[ii];
            float4 res = make_float4(o_r[ii][0] * inv, o_r[ii][1] * inv,
                                     o_r[ii][2] * inv, o_r[ii][3] * inv);
            *reinterpret_cast<float4*>(
                &ctx[(long)(b * SEQ + qi) * EMBED + h * HDIM + (tx << 2)]) = res;
        }
    }
}

// ---------------- Output projection: out = ctx @ proj_w^T + b ----------------
__global__ __launch_bounds__(256)
void proj_gemm_kernel(const float* __restrict__ ctxin, const float* __restrict__ w,
                      const float* __restrict__ bias, float* __restrict__ out)
{
    __shared__ float As[16][68];
    __shared__ float Bs[16][68];
    const int m0 = blockIdx.x * 64;
    const int n0 = blockIdx.y * 64;
    const int tid = threadIdx.x;
    const int tm = tid >> 4, tn = tid & 15;
    const int lr = tid >> 2, lc = (tid & 3) << 2;

    float acc[4][4] = {};
    const float* aptr = ctxin + (long)(m0 + lr) * EMBED + lc;
    const float* bptr = w + (long)(n0 + lr) * EMBED + lc;
    const bool avalid = (m0 + lr) < MROWS;

    for (int k0 = 0; k0 < EMBED; k0 += 16) {
        float4 av = make_float4(0.f, 0.f, 0.f, 0.f);
        if (avalid) av = *reinterpret_cast<const float4*>(aptr + k0);
        float4 bv = *reinterpret_cast<const float4*>(bptr + k0);
        As[lc + 0][lr] = av.x; As[lc + 1][lr] = av.y;
        As[lc + 2][lr] = av.z; As[lc + 3][lr] = av.w;
        Bs[lc + 0][lr] = bv.x; Bs[lc + 1][lr] = bv.y;
        Bs[lc + 2][lr] = bv.z; Bs[lc + 3][lr] = bv.w;
        __syncthreads();
        #pragma unroll
        for (int kk = 0; kk < 16; ++kk) {
            const float4 a4 = *reinterpret_cast<const float4*>(&As[kk][tm << 2]);
            const float4 b4 = *reinterpret_cast<const float4*>(&Bs[kk][tn << 2]);
            const float a[4] = {a4.x, a4.y, a4.z, a4.w};
            const float b[4] = {b4.x, b4.y, b4.z, b4.w};
            #pragma unroll
            for (int i = 0; i < 4; ++i)
                #pragma unroll
                for (int j = 0; j < 4; ++j)
                    acc[i][j] += a[i] * b[j];
        }
        __syncthreads();
    }

    const int nbase = n0 + (tn << 2);
    const float b0 = bias[nbase + 0], b1 = bias[nbase + 1];
    const float b2 = bias[nbase + 2], b3 = bias[nbase + 3];
    #pragma unroll
    for (int i = 0; i < 4; ++i) {
        int m = m0 + (tm << 2) + i;
        if (m >= MROWS) break;
        float4 res = make_float4(acc[i][0] + b0, acc[i][1] + b1,
                                 acc[i][2] + b2, acc[i][3] + b3);
        *reinterpret_cast<float4*>(&out[(long)m * EMBED + nbase]) = res;
    }
}

extern "C" void kernel_launch(void* const* d_in, const int* in_sizes, int n_in,
                              void* d_out, int out_size, void* d_ws, size_t ws_size,
                              hipStream_t stream) {
    const float* x       = (const float*)d_in[0];
    const float* qkv_w   = (const float*)d_in[1];
    const float* qkv_b   = (const float*)d_in[2];
    const float* proj_w  = (const float*)d_in[3];
    const float* proj_b  = (const float*)d_in[4];
    const float* rel_bt  = (const float*)d_in[5];
    const unsigned char* kmask = (const unsigned char*)d_in[6];  // numpy bool = 1 byte
    float* out = (float*)d_out;

    // workspace layout (floats): q,k,v,ctx each QKV_ELEMS; then cos/sin tables.
    // total = 4*6,297,600 + 2*65,536 floats = ~96.6 MiB
    float* ws   = (float*)d_ws;
    float* qbuf = ws;
    float* kbuf = qbuf + QKV_ELEMS;
    float* vbuf = kbuf + QKV_ELEMS;
    float* ctx  = vbuf + QKV_ELEMS;
    float* cosT = ctx + QKV_ELEMS;
    float* sinT = cosT + 1024 * HDIM;

    rope_table_kernel<<<1024, 64, 0, stream>>>(cosT, sinT);
    qkv_gemm_kernel<<<dim3((MROWS + 63) / 64, QKV_N / 64), 256, 0, stream>>>(
        x, qkv_w, qkv_b, cosT, sinT, qbuf, kbuf, vbuf);
    attn_kernel<<<dim3((SEQ + 63) / 64, BHCOUNT), 256, 0, stream>>>(
        qbuf, kbuf, vbuf, rel_bt, kmask, ctx);
    proj_gemm_kernel<<<dim3((MROWS + 63) / 64, EMBED / 64), 256, 0, stream>>>(
        ctx, proj_w, proj_b, out);
}

// Round 2
// 812.550 us; speedup vs baseline: 3.0966x; 3.0966x over previous
//
#include <hip/hip_runtime.h>
#include <math.h>

#define EMBED 768
#define NHEADS 12
#define HDIM 64
#define SEQ 1025
#define NBATCH 8
#define BHCOUNT (NBATCH*NHEADS)   // 96
#define MROWS (NBATCH*SEQ)        // 8200
#define QKV_N (3*EMBED)           // 2304
#define SCALE 0.125f
#define QKV_ELEMS (BHCOUNT*SEQ*HDIM)  // 6,297,600 elems per tensor

typedef __attribute__((ext_vector_type(8))) short bf16x8;
typedef __attribute__((ext_vector_type(4))) float f32x4;

static __device__ inline unsigned short f2bf(float f) {
    unsigned u = __float_as_uint(f);
    unsigned r = (u + 0x7FFF + ((u >> 16) & 1)) >> 16;   // RNE
    return (unsigned short)r;
}

// ---------------- RoPE tables: cos/sin [1024][64] ----------------
__global__ void rope_table_kernel(float* __restrict__ cosT, float* __restrict__ sinT) {
    int s = blockIdx.x;        // image token index 0..1023
    int d = threadIdx.x;       // 0..63
    int pos = (d < 32) ? (s >> 5) : (s & 31);   // row for first half, col for second
    int j = (d & 31) >> 1;                      // freq index 0..15
    float ang = (float)pos * expf(-(float)j * 0.5756462732485115f);
    cosT[(s << 6) + d] = cosf(ang);
    sinT[(s << 6) + d] = sinf(ang);
}

// ---------------- QKV GEMM: out = x @ qkv_w^T + b, fused RoPE + scatter ----------------
// x: [8200, 768], qkv_w: [2304, 768]. Writes q (pre-scaled), k, v as bf16 [B, H, S, D].
__global__ __launch_bounds__(256)
void qkv_gemm_kernel(const float* __restrict__ x, const float* __restrict__ w,
                     const float* __restrict__ bias,
                     const float* __restrict__ cosT, const float* __restrict__ sinT,
                     unsigned short* __restrict__ qout, unsigned short* __restrict__ kout,
                     unsigned short* __restrict__ vout)
{
    __shared__ float As[16][68];
    __shared__ float Bs[16][68];
    const int m0 = blockIdx.x * 64;
    const int n0 = blockIdx.y * 64;
    const int tid = threadIdx.x;
    const int tm = tid >> 4, tn = tid & 15;
    const int lr = tid >> 2, lc = (tid & 3) << 2;

    float acc[4][4] = {};
    const float* aptr = x + (long)(m0 + lr) * EMBED + lc;
    const float* bptr = w + (long)(n0 + lr) * EMBED + lc;
    const bool avalid = (m0 + lr) < MROWS;

    for (int k0 = 0; k0 < EMBED; k0 += 16) {
        float4 av = make_float4(0.f, 0.f, 0.f, 0.f);
        if (avalid) av = *reinterpret_cast<const float4*>(aptr + k0);
        float4 bv = *reinterpret_cast<const float4*>(bptr + k0);
        As[lc + 0][lr] = av.x; As[lc + 1][lr] = av.y;
        As[lc + 2][lr] = av.z; As[lc + 3][lr] = av.w;
        Bs[lc + 0][lr] = bv.x; Bs[lc + 1][lr] = bv.y;
        Bs[lc + 2][lr] = bv.z; Bs[lc + 3][lr] = bv.w;
        __syncthreads();
        #pragma unroll
        for (int kk = 0; kk < 16; ++kk) {
            const float4 a4 = *reinterpret_cast<const float4*>(&As[kk][tm << 2]);
            const float4 b4 = *reinterpret_cast<const float4*>(&Bs[kk][tn << 2]);
            const float a[4] = {a4.x, a4.y, a4.z, a4.w};
            const float b[4] = {b4.x, b4.y, b4.z, b4.w};
            #pragma unroll
            for (int i = 0; i < 4; ++i)
                #pragma unroll
                for (int j = 0; j < 4; ++j)
                    acc[i][j] += a[i] * b[j];
        }
        __syncthreads();
    }

    const int nbase = n0 + (tn << 2);
    const int which = nbase / EMBED;         // 0=q 1=k 2=v
    const int h = (nbase >> 6) % NHEADS;
    const int d0 = nbase & 63;               // multiple of 4, rope pairs in-thread
    unsigned short* outp = (which == 0) ? qout : (which == 1) ? kout : vout;
    const float mul = (which == 0) ? SCALE : 1.0f;
    const float b0 = bias[nbase + 0], b1 = bias[nbase + 1];
    const float b2 = bias[nbase + 2], b3 = bias[nbase + 3];

    #pragma unroll
    for (int i = 0; i < 4; ++i) {
        int m = m0 + (tm << 2) + i;
        if (m >= MROWS) break;
        int bb = m / SEQ, s = m - bb * SEQ;
        float v0 = acc[i][0] + b0, v1 = acc[i][1] + b1;
        float v2 = acc[i][2] + b2, v3 = acc[i][3] + b3;
        if (which < 2 && s >= 1) {
            int p = s - 1;
            const float* ct = cosT + (p << 6) + d0;
            const float* st = sinT + (p << 6) + d0;
            float c0 = ct[0], s0 = st[0], c2 = ct[2], s2 = st[2];
            float e = v0, o = v1;
            v0 = e * c0 - o * s0; v1 = o * c0 + e * s0;
            e = v2; o = v3;
            v2 = e * c2 - o * s2; v3 = o * c2 + e * s2;
        }
        ushort4 res;
        res.x = f2bf(v0 * mul); res.y = f2bf(v1 * mul);
        res.z = f2bf(v2 * mul); res.w = f2bf(v3 * mul);
        *reinterpret_cast<ushort4*>(
            &outp[((long)bb * NHEADS + h) * (SEQ * HDIM) + (long)s * HDIM + d0]) = res;
    }
}

// ---------------- Flash attention, bf16 MFMA, with rel-pos bias ----------------
// grid: (17 q-tiles, 96 b*h), block 256 (4 waves). q/k/v bf16 [B,H,S,D]; q pre-scaled.
// Each wave owns a 16-row q strip. LDS tiles XOR-swizzled: col ^= (row&7)<<3.
__global__ __launch_bounds__(256)
void attn_mfma_kernel(const unsigned short* __restrict__ qg,
                      const unsigned short* __restrict__ kg,
                      const unsigned short* __restrict__ vg,
                      const float* __restrict__ bt,
                      const unsigned char* __restrict__ mask,
                      float* __restrict__ ctx)
{
    __shared__ unsigned short Qs[64][64];    // [q][d]
    __shared__ unsigned short Ks[64][64];    // [k][d]
    __shared__ unsigned short Vts[64][64];   // [d][k] (transposed)
    __shared__ unsigned short Ps[4][16][64]; // per-wave P strip [q_local][k]

    const int q0 = blockIdx.x * 64;
    const int bh = (int)blockIdx.y;
    const int b = bh / NHEADS, h = bh % NHEADS;
    const int tid = threadIdx.x;
    const int w = tid >> 6;
    const int lane = tid & 63;
    const int lg = lane >> 4;    // k-fragment group 0..3
    const int li = lane & 15;

    const unsigned short* qbase = qg + (long)bh * (SEQ * HDIM);
    const unsigned short* kbase = kg + (long)bh * (SEQ * HDIM);
    const unsigned short* vbase = vg + (long)bh * (SEQ * HDIM);
    const unsigned char* maskp = mask + b * SEQ;

    // ---- stage Q (swizzled bf16) ----
    for (int i = tid; i < 512; i += 256) {
        int r = i >> 3, c8 = (i & 7) << 3;
        int qi = q0 + r;
        int4 val = make_int4(0, 0, 0, 0);
        if (qi < SEQ) val = *reinterpret_cast<const int4*>(&qbase[(long)qi * HDIM + c8]);
        *reinterpret_cast<int4*>(&Qs[r][c8 ^ ((r & 7) << 3)]) = val;
    }

    float m_r[4], l_r[4];
    f32x4 acco[4];
    #pragma unroll
    for (int r = 0; r < 4; ++r) { m_r[r] = -1e30f; l_r[r] = 0.f; }
    #pragma unroll
    for (int j = 0; j < 4; ++j) acco[j] = (f32x4){0.f, 0.f, 0.f, 0.f};

    for (int kt = 0; kt < 17; ++kt) {
        const int k0 = kt * 64;
        __syncthreads();   // prev iter's Ks/Vts reads done (first iter: covers Q staging)

        // ---- stage K and V^T ----
        for (int i = tid; i < 512; i += 256) {
            int r = i >> 3, c8 = (i & 7) << 3;
            int ki = k0 + r;
            int4 kv = make_int4(0, 0, 0, 0);
            int4 vv = make_int4(0, 0, 0, 0);
            if (ki < SEQ) {
                kv = *reinterpret_cast<const int4*>(&kbase[(long)ki * HDIM + c8]);
                vv = *reinterpret_cast<const int4*>(&vbase[(long)ki * HDIM + c8]);
            }
            *reinterpret_cast<int4*>(&Ks[r][c8 ^ ((r & 7) << 3)]) = kv;
            union { int4 v; unsigned short u[8]; } t; t.v = vv;
            #pragma unroll
            for (int e = 0; e < 8; ++e)
                Vts[c8 + e][r ^ (e << 3)] = t.u[e];   // row=c8+e, (row&7)=e
        }
        __syncthreads();

        // ---- QK^T: S[16][64] strip per wave ----
        f32x4 accs[4];
        #pragma unroll
        for (int j = 0; j < 4; ++j) accs[j] = (f32x4){0.f, 0.f, 0.f, 0.f};
        #pragma unroll
        for (int dk = 0; dk < 64; dk += 32) {
            const int cb = dk + (lg << 3);
            const int qrow = (w << 4) + li;
            bf16x8 a = *reinterpret_cast<const bf16x8*>(&Qs[qrow][cb ^ ((li & 7) << 3)]);
            #pragma unroll
            for (int j = 0; j < 4; ++j) {
                const int krow = (j << 4) + li;
                bf16x8 bfrag = *reinterpret_cast<const bf16x8*>(&Ks[krow][cb ^ ((li & 7) << 3)]);
                accs[j] = __builtin_amdgcn_mfma_f32_16x16x32_bf16(a, bfrag, accs[j], 0, 0, 0);
            }
        }

        // ---- bias + mask + online softmax ----
        // element (j,r): row_local=(lg<<2)+r, col=(j<<4)+li
        float alpha[4];
        #pragma unroll
        for (int r = 0; r < 4; ++r) {
            const int rl = (lg << 2) + r;
            const int qi = q0 + (w << 4) + rl;
            float sr[4];
            #pragma unroll
            for (int j = 0; j < 4; ++j) {
                const int ki = k0 + (j << 4) + li;
                float s = accs[j][r];
                if (qi >= SEQ || ki >= SEQ) {
                    s = -1e30f;
                } else {
                    if (qi >= 1 && ki >= 1) {
                        int qp = qi - 1, kp = ki - 1;
                        int idx = ((qp >> 5) - (kp >> 5) + 31) * 63 +
                                  ((qp & 31) - (kp & 31) + 31);
                        s += bt[idx * NHEADS + h];
                    }
                    if (maskp[ki]) s = -1e30f;
                }
                sr[j] = s;
            }
            float mx = fmaxf(fmaxf(sr[0], sr[1]), fmaxf(sr[2], sr[3]));
            #pragma unroll
            for (int off = 1; off < 16; off <<= 1)
                mx = fmaxf(mx, __shfl_xor(mx, off, 64));
            float mnew = fmaxf(m_r[r], mx);
            alpha[r] = __expf(m_r[r] - mnew);
            float rs = 0.f;
            #pragma unroll
            for (int j = 0; j < 4; ++j) {
                float p = __expf(sr[j] - mnew);
                rs += p;
                Ps[w][rl][((j << 4) + li) ^ ((rl & 7) << 3)] = f2bf(p);
            }
            #pragma unroll
            for (int off = 1; off < 16; off <<= 1)
                rs += __shfl_xor(rs, off, 64);
            l_r[r] = l_r[r] * alpha[r] + rs;
            m_r[r] = mnew;
        }

        // rescale O accumulators (acc row r <-> softmax row r, same D-layout)
        #pragma unroll
        for (int j = 0; j < 4; ++j)
            #pragma unroll
            for (int r = 0; r < 4; ++r)
                acco[j][r] *= alpha[r];

        // ---- PV: O[16][64] += P[16][64] * V[64][64]  (wave-local Ps, no barrier) ----
        #pragma unroll
        for (int kk = 0; kk < 64; kk += 32) {
            const int cb = kk + (lg << 3);
            bf16x8 a = *reinterpret_cast<const bf16x8*>(&Ps[w][li][cb ^ ((li & 7) << 3)]);
            #pragma unroll
            for (int j = 0; j < 4; ++j) {
                const int drow = (j << 4) + li;
                bf16x8 bfrag = *reinterpret_cast<const bf16x8*>(&Vts[drow][cb ^ ((li & 7) << 3)]);
                acco[j] = __builtin_amdgcn_mfma_f32_16x16x32_bf16(a, bfrag, acco[j], 0, 0, 0);
            }
        }
    }

    // ---- epilogue: ctx[b, qi, h*64 + col] = O / l ----
    #pragma unroll
    for (int r = 0; r < 4; ++r) {
        const int rl = (lg << 2) + r;
        const int qi = q0 + (w << 4) + rl;
        if (qi < SEQ) {
            const float inv = 1.0f / l_r[r];
            #pragma unroll
            for (int j = 0; j < 4; ++j)
                ctx[(long)(b * SEQ + qi) * EMBED + h * HDIM + (j << 4) + li] =
                    acco[j][r] * inv;
        }
    }
}

// ---------------- Output projection: out = ctx @ proj_w^T + b ----------------
__global__ __launch_bounds__(256)
void proj_gemm_kernel(const float* __restrict__ ctxin, const float* __restrict__ w,
                      const float* __restrict__ bias, float* __restrict__ out)
{
    __shared__ float As[16][68];
    __shared__ float Bs[16][68];
    const int m0 = blockIdx.x * 64;
    const int n0 = blockIdx.y * 64;
    const int tid = threadIdx.x;
    const int tm = tid >> 4, tn = tid & 15;
    const int lr = tid >> 2, lc = (tid & 3) << 2;

    float acc[4][4] = {};
    const float* aptr = ctxin + (long)(m0 + lr) * EMBED + lc;
    const float* bptr = w + (long)(n0 + lr) * EMBED + lc;
    const bool avalid = (m0 + lr) < MROWS;

    for (int k0 = 0; k0 < EMBED; k0 += 16) {
        float4 av = make_float4(0.f, 0.f, 0.f, 0.f);
        if (avalid) av = *reinterpret_cast<const float4*>(aptr + k0);
        float4 bv = *reinterpret_cast<const float4*>(bptr + k0);
        As[lc + 0][lr] = av.x; As[lc + 1][lr] = av.y;
        As[lc + 2][lr] = av.z; As[lc + 3][lr] = av.w;
        Bs[lc + 0][lr] = bv.x; Bs[lc + 1][lr] = bv.y;
        Bs[lc + 2][lr] = bv.z; Bs[lc + 3][lr] = bv.w;
        __syncthreads();
        #pragma unroll
        for (int kk = 0; kk < 16; ++kk) {
            const float4 a4 = *reinterpret_cast<const float4*>(&As[kk][tm << 2]);
            const float4 b4 = *reinterpret_cast<const float4*>(&Bs[kk][tn << 2]);
            const float a[4] = {a4.x, a4.y, a4.z, a4.w};
            const float b[4] = {b4.x, b4.y, b4.z, b4.w};
            #pragma unroll
            for (int i = 0; i < 4; ++i)
                #pragma unroll
                for (int j = 0; j < 4; ++j)
                    acc[i][j] += a[i] * b[j];
        }
        __syncthreads();
    }

    const int nbase = n0 + (tn << 2);
    const float b0 = bias[nbase + 0], b1 = bias[nbase + 1];
    const float b2 = bias[nbase + 2], b3 = bias[nbase + 3];
    #pragma unroll
    for (int i = 0; i < 4; ++i) {
        int m = m0 + (tm << 2) + i;
        if (m >= MROWS) break;
        float4 res = make_float4(acc[i][0] + b0, acc[i][1] + b1,
                                 acc[i][2] + b2, acc[i][3] + b3);
        *reinterpret_cast<float4*>(&out[(long)m * EMBED + nbase]) = res;
    }
}

extern "C" void kernel_launch(void* const* d_in, const int* in_sizes, int n_in,
                              void* d_out, int out_size, void* d_ws, size_t ws_size,
                              hipStream_t stream) {
    const float* x       = (const float*)d_in[0];
    const float* qkv_w   = (const float*)d_in[1];
    const float* qkv_b   = (const float*)d_in[2];
    const float* proj_w  = (const float*)d_in[3];
    const float* proj_b  = (const float*)d_in[4];
    const float* rel_bt  = (const float*)d_in[5];
    const unsigned char* kmask = (const unsigned char*)d_in[6];
    float* out = (float*)d_out;

    // workspace: q,k,v bf16 (12.6 MB each), ctx fp32 (25.2 MB), rope tables
    unsigned short* qbuf = (unsigned short*)d_ws;
    unsigned short* kbuf = qbuf + QKV_ELEMS;
    unsigned short* vbuf = kbuf + QKV_ELEMS;
    float* ctx  = (float*)(vbuf + QKV_ELEMS);
    float* cosT = ctx + QKV_ELEMS;
    float* sinT = cosT + 1024 * HDIM;

    rope_table_kernel<<<1024, 64, 0, stream>>>(cosT, sinT);
    qkv_gemm_kernel<<<dim3((MROWS + 63) / 64, QKV_N / 64), 256, 0, stream>>>(
        x, qkv_w, qkv_b, cosT, sinT, qbuf, kbuf, vbuf);
    attn_mfma_kernel<<<dim3((SEQ + 63) / 64, BHCOUNT), 256, 0, stream>>>(
        qbuf, kbuf, vbuf, rel_bt, kmask, ctx);
    proj_gemm_kernel<<<dim3((MROWS + 63) / 64, EMBED / 64), 256, 0, stream>>>(
        ctx, proj_w, proj_b, out);
}

// Round 3
// 384.398 us; speedup vs baseline: 6.5457x; 2.1138x over previous
//
#include <hip/hip_runtime.h>
#include <math.h>

#define EMBED 768
#define NHEADS 12
#define HDIM 64
#define SEQ 1025
#define NBATCH 8
#define BHCOUNT (NBATCH*NHEADS)   // 96
#define MROWS (NBATCH*SEQ)        // 8200
#define QKV_N (3*EMBED)           // 2304
#define SCALE 0.125f
#define QKV_ELEMS (BHCOUNT*SEQ*HDIM)  // 6,297,600 elems (== MROWS*EMBED)

typedef __attribute__((ext_vector_type(8))) short bf16x8;
typedef __attribute__((ext_vector_type(4))) float f32x4;

static __device__ inline unsigned short f2bf(float f) {
    unsigned u = __float_as_uint(f);
    unsigned r = (u + 0x7FFF + ((u >> 16) & 1)) >> 16;   // RNE
    return (unsigned short)r;
}

// async global->LDS, 16B per lane, linear LDS dest (wave-uniform base + lane*16)
static __device__ inline void gld16(const unsigned short* g, unsigned short* l) {
    __builtin_amdgcn_global_load_lds(
        (const __attribute__((address_space(1))) unsigned int*)g,
        (__attribute__((address_space(3))) unsigned int*)l,
        16, 0, 0);
}

// ---------------- fp32 -> bf16 convert (vectorized, n % 4 == 0) ----------------
__global__ __launch_bounds__(256)
void f2bf_kernel(const float* __restrict__ src, unsigned short* __restrict__ dst, int n4) {
    int i = blockIdx.x * 256 + threadIdx.x;
    if (i < n4) {
        float4 v = *reinterpret_cast<const float4*>(&src[i << 2]);
        ushort4 o;
        o.x = f2bf(v.x); o.y = f2bf(v.y); o.z = f2bf(v.z); o.w = f2bf(v.w);
        *reinterpret_cast<ushort4*>(&dst[i << 2]) = o;
    }
}

// ---------------- RoPE tables: cos/sin [1024][64] ----------------
__global__ void rope_table_kernel(float* __restrict__ cosT, float* __restrict__ sinT) {
    int s = blockIdx.x;
    int d = threadIdx.x;
    int pos = (d < 32) ? (s >> 5) : (s & 31);
    int j = (d & 31) >> 1;
    float ang = (float)pos * expf(-(float)j * 0.5756462732485115f);
    cosT[(s << 6) + d] = cosf(ang);
    sinT[(s << 6) + d] = sinf(ang);
}

// ---------------- QKV GEMM (bf16 MFMA, m97 structure) ----------------
// xbf [8200][768], wbf [2304][768]; C = x @ w^T + b, fused RoPE + scatter to
// q (pre-scaled) / k / v bf16 [B,H,S,D]. 128x128 tile, BK=32, 4 waves (2x2 of 64x64).
__global__ __launch_bounds__(256)
void qkv_mfma_kernel(const unsigned short* __restrict__ xbf,
                     const unsigned short* __restrict__ wbf,
                     const float* __restrict__ bias,
                     const float* __restrict__ cosT, const float* __restrict__ sinT,
                     unsigned short* __restrict__ qout, unsigned short* __restrict__ kout,
                     unsigned short* __restrict__ vout)
{
    __shared__ unsigned short As[128][32];
    __shared__ unsigned short Bs[128][32];
    const int m0 = blockIdx.x * 128;
    const int n0 = blockIdx.y * 128;
    const int tid = threadIdx.x;
    const int w = tid >> 6, lane = tid & 63;
    const int li = lane & 15, lg = lane >> 4;
    const int wr = w >> 1, wc = w & 1;

    f32x4 acc[4][4];
    #pragma unroll
    for (int mi = 0; mi < 4; ++mi)
        #pragma unroll
        for (int nj = 0; nj < 4; ++nj) acc[mi][nj] = (f32x4){0.f, 0.f, 0.f, 0.f};

    for (int kt = 0; kt < 24; ++kt) {
        const int k0 = kt << 5;
        #pragma unroll
        for (int c = 0; c < 2; ++c) {
            const int idx = c * 256 + tid;       // 0..511
            const int row = idx >> 2, slot = idx & 3;
            int grow = m0 + row; if (grow > MROWS - 1) grow = MROWS - 1;
            gld16(&xbf[(long)grow * EMBED + k0 + slot * 8], &As[0][0] + idx * 8);
            gld16(&wbf[(long)(n0 + row) * EMBED + k0 + slot * 8], &Bs[0][0] + idx * 8);
        }
        __syncthreads();

        bf16x8 af[4], bfr[4];
        #pragma unroll
        for (int mi = 0; mi < 4; ++mi)
            af[mi] = *reinterpret_cast<const bf16x8*>(&As[wr * 64 + mi * 16 + li][lg * 8]);
        #pragma unroll
        for (int nj = 0; nj < 4; ++nj)
            bfr[nj] = *reinterpret_cast<const bf16x8*>(&Bs[wc * 64 + nj * 16 + li][lg * 8]);
        #pragma unroll
        for (int mi = 0; mi < 4; ++mi)
            #pragma unroll
            for (int nj = 0; nj < 4; ++nj)
                acc[mi][nj] = __builtin_amdgcn_mfma_f32_16x16x32_bf16(
                    af[mi], bfr[nj], acc[mi][nj], 0, 0, 0);
        __syncthreads();
    }

    // rows don't depend on nj: precompute batch/seq decomposition
    int brow[4][4], srow[4][4];
    #pragma unroll
    for (int mi = 0; mi < 4; ++mi)
        #pragma unroll
        for (int r = 0; r < 4; ++r) {
            int m = m0 + wr * 64 + mi * 16 + lg * 4 + r;
            int mm = (m < MROWS) ? m : (MROWS - 1);
            int bb = mm / SEQ;
            brow[mi][r] = bb;
            srow[mi][r] = mm - bb * SEQ;
        }

    #pragma unroll
    for (int nj = 0; nj < 4; ++nj) {
        const int n = n0 + wc * 64 + nj * 16 + li;
        const int which = n / EMBED;             // 0=q 1=k 2=v (uniform per frag)
        const int nh = n - which * EMBED;
        const int h = nh >> 6, d = nh & 63;
        unsigned short* outp = (which == 0) ? qout : (which == 1) ? kout : vout;
        const float mul = (which == 0) ? SCALE : 1.0f;
        const float bn = bias[n];
        const bool dorope = which < 2;
        const float sgn = (d & 1) ? 1.f : -1.f;
        #pragma unroll
        for (int mi = 0; mi < 4; ++mi)
            #pragma unroll
            for (int r = 0; r < 4; ++r) {
                const int m = m0 + wr * 64 + mi * 16 + lg * 4 + r;
                float v = acc[mi][nj][r] + bn;
                float pv = __shfl_xor(v, 1, 64);   // partner d^1 (same m-guard state)
                if (m < MROWS) {
                    const int bb = brow[mi][r], s = srow[mi][r];
                    if (dorope && s >= 1) {
                        const int p = s - 1;
                        v = v * cosT[(p << 6) + d] + sgn * pv * sinT[(p << 6) + d];
                    }
                    outp[((long)(bb * NHEADS + h) * SEQ + s) * HDIM + d] = f2bf(v * mul);
                }
            }
    }
}

// ---------------- Flash attention, bf16 MFMA, with rel-pos bias ----------------
__global__ __launch_bounds__(256)
void attn_mfma_kernel(const unsigned short* __restrict__ qg,
                      const unsigned short* __restrict__ kg,
                      const unsigned short* __restrict__ vg,
                      const float* __restrict__ bt,
                      const unsigned char* __restrict__ mask,
                      unsigned short* __restrict__ ctx)
{
    __shared__ unsigned short Qs[64][64];
    __shared__ unsigned short Ks[64][64];
    __shared__ unsigned short Vts[64][64];
    __shared__ unsigned short Ps[4][16][64];

    const int q0 = blockIdx.x * 64;
    const int bh = (int)blockIdx.y;
    const int b = bh / NHEADS, h = bh % NHEADS;
    const int tid = threadIdx.x;
    const int w = tid >> 6;
    const int lane = tid & 63;
    const int lg = lane >> 4;
    const int li = lane & 15;

    const unsigned short* qbase = qg + (long)bh * (SEQ * HDIM);
    const unsigned short* kbase = kg + (long)bh * (SEQ * HDIM);
    const unsigned short* vbase = vg + (long)bh * (SEQ * HDIM);
    const unsigned char* maskp = mask + b * SEQ;

    for (int i = tid; i < 512; i += 256) {
        int r = i >> 3, c8 = (i & 7) << 3;
        int qi = q0 + r;
        int4 val = make_int4(0, 0, 0, 0);
        if (qi < SEQ) val = *reinterpret_cast<const int4*>(&qbase[(long)qi * HDIM + c8]);
        *reinterpret_cast<int4*>(&Qs[r][c8 ^ ((r & 7) << 3)]) = val;
    }

    float m_r[4], l_r[4];
    f32x4 acco[4];
    #pragma unroll
    for (int r = 0; r < 4; ++r) { m_r[r] = -1e30f; l_r[r] = 0.f; }
    #pragma unroll
    for (int j = 0; j < 4; ++j) acco[j] = (f32x4){0.f, 0.f, 0.f, 0.f};

    for (int kt = 0; kt < 17; ++kt) {
        const int k0 = kt * 64;
        __syncthreads();

        for (int i = tid; i < 512; i += 256) {
            int r = i >> 3, c8 = (i & 7) << 3;
            int ki = k0 + r;
            int4 kv = make_int4(0, 0, 0, 0);
            int4 vv = make_int4(0, 0, 0, 0);
            if (ki < SEQ) {
                kv = *reinterpret_cast<const int4*>(&kbase[(long)ki * HDIM + c8]);
                vv = *reinterpret_cast<const int4*>(&vbase[(long)ki * HDIM + c8]);
            }
            *reinterpret_cast<int4*>(&Ks[r][c8 ^ ((r & 7) << 3)]) = kv;
            union { int4 v; unsigned short u[8]; } t; t.v = vv;
            #pragma unroll
            for (int e = 0; e < 8; ++e)
                Vts[c8 + e][r ^ (e << 3)] = t.u[e];
        }
        __syncthreads();

        f32x4 accs[4];
        #pragma unroll
        for (int j = 0; j < 4; ++j) accs[j] = (f32x4){0.f, 0.f, 0.f, 0.f};
        #pragma unroll
        for (int dk = 0; dk < 64; dk += 32) {
            const int cb = dk + (lg << 3);
            const int qrow = (w << 4) + li;
            bf16x8 a = *reinterpret_cast<const bf16x8*>(&Qs[qrow][cb ^ ((li & 7) << 3)]);
            #pragma unroll
            for (int j = 0; j < 4; ++j) {
                const int krow = (j << 4) + li;
                bf16x8 bfrag = *reinterpret_cast<const bf16x8*>(&Ks[krow][cb ^ ((li & 7) << 3)]);
                accs[j] = __builtin_amdgcn_mfma_f32_16x16x32_bf16(a, bfrag, accs[j], 0, 0, 0);
            }
        }

        float alpha[4];
        #pragma unroll
        for (int r = 0; r < 4; ++r) {
            const int rl = (lg << 2) + r;
            const int qi = q0 + (w << 4) + rl;
            float sr[4];
            #pragma unroll
            for (int j = 0; j < 4; ++j) {
                const int ki = k0 + (j << 4) + li;
                float s = accs[j][r];
                if (qi >= SEQ || ki >= SEQ) {
                    s = -1e30f;
                } else {
                    if (qi >= 1 && ki >= 1) {
                        int qp = qi - 1, kp = ki - 1;
                        int idx = ((qp >> 5) - (kp >> 5) + 31) * 63 +
                                  ((qp & 31) - (kp & 31) + 31);
                        s += bt[idx * NHEADS + h];
                    }
                    if (maskp[ki]) s = -1e30f;
                }
                sr[j] = s;
            }
            float mx = fmaxf(fmaxf(sr[0], sr[1]), fmaxf(sr[2], sr[3]));
            #pragma unroll
            for (int off = 1; off < 16; off <<= 1)
                mx = fmaxf(mx, __shfl_xor(mx, off, 64));
            float mnew = fmaxf(m_r[r], mx);
            alpha[r] = __expf(m_r[r] - mnew);
            float rs = 0.f;
            #pragma unroll
            for (int j = 0; j < 4; ++j) {
                float p = __expf(sr[j] - mnew);
                rs += p;
                Ps[w][rl][((j << 4) + li) ^ ((rl & 7) << 3)] = f2bf(p);
            }
            #pragma unroll
            for (int off = 1; off < 16; off <<= 1)
                rs += __shfl_xor(rs, off, 64);
            l_r[r] = l_r[r] * alpha[r] + rs;
            m_r[r] = mnew;
        }

        #pragma unroll
        for (int j = 0; j < 4; ++j)
            #pragma unroll
            for (int r = 0; r < 4; ++r)
                acco[j][r] *= alpha[r];

        #pragma unroll
        for (int kk = 0; kk < 64; kk += 32) {
            const int cb = kk + (lg << 3);
            bf16x8 a = *reinterpret_cast<const bf16x8*>(&Ps[w][li][cb ^ ((li & 7) << 3)]);
            #pragma unroll
            for (int j = 0; j < 4; ++j) {
                const int drow = (j << 4) + li;
                bf16x8 bfrag = *reinterpret_cast<const bf16x8*>(&Vts[drow][cb ^ ((li & 7) << 3)]);
                acco[j] = __builtin_amdgcn_mfma_f32_16x16x32_bf16(a, bfrag, acco[j], 0, 0, 0);
            }
        }
    }

    #pragma unroll
    for (int r = 0; r < 4; ++r) {
        const int rl = (lg << 2) + r;
        const int qi = q0 + (w << 4) + rl;
        if (qi < SEQ) {
            const float inv = 1.0f / l_r[r];
            #pragma unroll
            for (int j = 0; j < 4; ++j)
                ctx[(long)(b * SEQ + qi) * EMBED + h * HDIM + (j << 4) + li] =
                    f2bf(acco[j][r] * inv);
        }
    }
}

// ---------------- Output projection (bf16 MFMA): out = ctx @ proj_w^T + b ----------------
__global__ __launch_bounds__(256)
void proj_mfma_kernel(const unsigned short* __restrict__ ctxbf,
                      const unsigned short* __restrict__ pwbf,
                      const float* __restrict__ bias, float* __restrict__ out)
{
    __shared__ unsigned short As[128][32];
    __shared__ unsigned short Bs[128][32];
    const int m0 = blockIdx.x * 128;
    const int n0 = blockIdx.y * 128;
    const int tid = threadIdx.x;
    const int w = tid >> 6, lane = tid & 63;
    const int li = lane & 15, lg = lane >> 4;
    const int wr = w >> 1, wc = w & 1;

    f32x4 acc[4][4];
    #pragma unroll
    for (int mi = 0; mi < 4; ++mi)
        #pragma unroll
        for (int nj = 0; nj < 4; ++nj) acc[mi][nj] = (f32x4){0.f, 0.f, 0.f, 0.f};

    for (int kt = 0; kt < 24; ++kt) {
        const int k0 = kt << 5;
        #pragma unroll
        for (int c = 0; c < 2; ++c) {
            const int idx = c * 256 + tid;
            const int row = idx >> 2, slot = idx & 3;
            int grow = m0 + row; if (grow > MROWS - 1) grow = MROWS - 1;
            gld16(&ctxbf[(long)grow * EMBED + k0 + slot * 8], &As[0][0] + idx * 8);
            gld16(&pwbf[(long)(n0 + row) * EMBED + k0 + slot * 8], &Bs[0][0] + idx * 8);
        }
        __syncthreads();

        bf16x8 af[4], bfr[4];
        #pragma unroll
        for (int mi = 0; mi < 4; ++mi)
            af[mi] = *reinterpret_cast<const bf16x8*>(&As[wr * 64 + mi * 16 + li][lg * 8]);
        #pragma unroll
        for (int nj = 0; nj < 4; ++nj)
            bfr[nj] = *reinterpret_cast<const bf16x8*>(&Bs[wc * 64 + nj * 16 + li][lg * 8]);
        #pragma unroll
        for (int mi = 0; mi < 4; ++mi)
            #pragma unroll
            for (int nj = 0; nj < 4; ++nj)
                acc[mi][nj] = __builtin_amdgcn_mfma_f32_16x16x32_bf16(
                    af[mi], bfr[nj], acc[mi][nj], 0, 0, 0);
        __syncthreads();
    }

    #pragma unroll
    for (int nj = 0; nj < 4; ++nj) {
        const int n = n0 + wc * 64 + nj * 16 + li;
        const float bn = bias[n];
        #pragma unroll
        for (int mi = 0; mi < 4; ++mi)
            #pragma unroll
            for (int r = 0; r < 4; ++r) {
                const int m = m0 + wr * 64 + mi * 16 + lg * 4 + r;
                if (m < MROWS)
                    out[(long)m * EMBED + n] = acc[mi][nj][r] + bn;
            }
    }
}

extern "C" void kernel_launch(void* const* d_in, const int* in_sizes, int n_in,
                              void* d_out, int out_size, void* d_ws, size_t ws_size,
                              hipStream_t stream) {
    const float* x       = (const float*)d_in[0];
    const float* qkv_w   = (const float*)d_in[1];
    const float* qkv_b   = (const float*)d_in[2];
    const float* proj_w  = (const float*)d_in[3];
    const float* proj_b  = (const float*)d_in[4];
    const float* rel_bt  = (const float*)d_in[5];
    const unsigned char* kmask = (const unsigned char*)d_in[6];
    float* out = (float*)d_out;

    // workspace (ushort units): q,k,v,ctx,xbf = QKV_ELEMS each; wbf; pwbf; fp32 tables
    unsigned short* qbuf  = (unsigned short*)d_ws;
    unsigned short* kbuf  = qbuf + QKV_ELEMS;
    unsigned short* vbuf  = kbuf + QKV_ELEMS;
    unsigned short* ctxbf = vbuf + QKV_ELEMS;
    unsigned short* xbf   = ctxbf + QKV_ELEMS;
    unsigned short* wbf   = xbf + QKV_ELEMS;            // 2304*768
    unsigned short* pwbf  = wbf + QKV_N * EMBED;        // 768*768
    float* cosT = (float*)(pwbf + EMBED * EMBED);
    float* sinT = cosT + 1024 * HDIM;

    const int nx = MROWS * EMBED / 4;          // 1,574,400
    const int nw = QKV_N * EMBED / 4;          // 442,368
    const int np = EMBED * EMBED / 4;          // 147,456
    f2bf_kernel<<<(nx + 255) / 256, 256, 0, stream>>>(x, xbf, nx);
    f2bf_kernel<<<(nw + 255) / 256, 256, 0, stream>>>(qkv_w, wbf, nw);
    f2bf_kernel<<<(np + 255) / 256, 256, 0, stream>>>(proj_w, pwbf, np);
    rope_table_kernel<<<1024, 64, 0, stream>>>(cosT, sinT);

    qkv_mfma_kernel<<<dim3((MROWS + 127) / 128, QKV_N / 128), 256, 0, stream>>>(
        xbf, wbf, qkv_b, cosT, sinT, qbuf, kbuf, vbuf);
    attn_mfma_kernel<<<dim3((SEQ + 63) / 64, BHCOUNT), 256, 0, stream>>>(
        qbuf, kbuf, vbuf, rel_bt, kmask, ctxbf);
    proj_mfma_kernel<<<dim3((MROWS + 127) / 128, EMBED / 128), 256, 0, stream>>>(
        ctxbf, pwbf, proj_b, out);
}

// Round 4
// 342.823 us; speedup vs baseline: 7.3395x; 1.1213x over previous
//
#include <hip/hip_runtime.h>
#include <math.h>

#define EMBED 768
#define NHEADS 12
#define HDIM 64
#define SEQ 1025
#define NBATCH 8
#define BHCOUNT (NBATCH*NHEADS)   // 96
#define MROWS (NBATCH*SEQ)        // 8200
#define QKV_N (3*EMBED)           // 2304
#define SCALE 0.125f
#define QKV_ELEMS (BHCOUNT*SEQ*HDIM)  // 6,297,600 elems (== MROWS*EMBED)
#define BT_N 3969                 // (2*32-1)^2

typedef __attribute__((ext_vector_type(8))) short bf16x8;
typedef __attribute__((ext_vector_type(4))) float f32x4;

static __device__ inline unsigned short f2bf(float f) {
    unsigned u = __float_as_uint(f);
    unsigned r = (u + 0x7FFF + ((u >> 16) & 1)) >> 16;   // RNE
    return (unsigned short)r;
}

// async global->LDS, 16B per lane, linear LDS dest (wave-uniform base + lane*16)
static __device__ inline void gld16(const unsigned short* g, unsigned short* l) {
    __builtin_amdgcn_global_load_lds(
        (const __attribute__((address_space(1))) unsigned int*)g,
        (__attribute__((address_space(3))) unsigned int*)l,
        16, 0, 0);
}

// ---------------- fp32 -> bf16 convert (vectorized, n % 4 == 0) ----------------
__global__ __launch_bounds__(256)
void f2bf_kernel(const float* __restrict__ src, unsigned short* __restrict__ dst, int n4) {
    int i = blockIdx.x * 256 + threadIdx.x;
    if (i < n4) {
        float4 v = *reinterpret_cast<const float4*>(&src[i << 2]);
        ushort4 o;
        o.x = f2bf(v.x); o.y = f2bf(v.y); o.z = f2bf(v.z); o.w = f2bf(v.w);
        *reinterpret_cast<ushort4*>(&dst[i << 2]) = o;
    }
}

// ---------------- RoPE tables: cos/sin [1024][64] ----------------
__global__ void rope_table_kernel(float* __restrict__ cosT, float* __restrict__ sinT) {
    int s = blockIdx.x;
    int d = threadIdx.x;
    int pos = (d < 32) ? (s >> 5) : (s & 31);
    int j = (d & 31) >> 1;
    float ang = (float)pos * expf(-(float)j * 0.5756462732485115f);
    cosT[(s << 6) + d] = cosf(ang);
    sinT[(s << 6) + d] = sinf(ang);
}

// ---------------- bias table transpose: btT[h][3969] ----------------
__global__ __launch_bounds__(256)
void bt_transpose_kernel(const float* __restrict__ bt, float* __restrict__ btT) {
    int e = blockIdx.x * 256 + threadIdx.x;
    int h = blockIdx.y;
    if (e < BT_N) btT[h * BT_N + e] = bt[e * NHEADS + h];
}

// ---------------- QKV GEMM (bf16 MFMA, m97 structure) ----------------
__global__ __launch_bounds__(256)
void qkv_mfma_kernel(const unsigned short* __restrict__ xbf,
                     const unsigned short* __restrict__ wbf,
                     const float* __restrict__ bias,
                     const float* __restrict__ cosT, const float* __restrict__ sinT,
                     unsigned short* __restrict__ qout, unsigned short* __restrict__ kout,
                     unsigned short* __restrict__ vout)
{
    __shared__ unsigned short As[128][32];
    __shared__ unsigned short Bs[128][32];
    const int m0 = blockIdx.x * 128;
    const int n0 = blockIdx.y * 128;
    const int tid = threadIdx.x;
    const int w = tid >> 6, lane = tid & 63;
    const int li = lane & 15, lg = lane >> 4;
    const int wr = w >> 1, wc = w & 1;

    f32x4 acc[4][4];
    #pragma unroll
    for (int mi = 0; mi < 4; ++mi)
        #pragma unroll
        for (int nj = 0; nj < 4; ++nj) acc[mi][nj] = (f32x4){0.f, 0.f, 0.f, 0.f};

    for (int kt = 0; kt < 24; ++kt) {
        const int k0 = kt << 5;
        #pragma unroll
        for (int c = 0; c < 2; ++c) {
            const int idx = c * 256 + tid;       // 0..511
            const int row = idx >> 2, slot = idx & 3;
            int grow = m0 + row; if (grow > MROWS - 1) grow = MROWS - 1;
            gld16(&xbf[(long)grow * EMBED + k0 + slot * 8], &As[0][0] + idx * 8);
            gld16(&wbf[(long)(n0 + row) * EMBED + k0 + slot * 8], &Bs[0][0] + idx * 8);
        }
        __syncthreads();

        bf16x8 af[4], bfr[4];
        #pragma unroll
        for (int mi = 0; mi < 4; ++mi)
            af[mi] = *reinterpret_cast<const bf16x8*>(&As[wr * 64 + mi * 16 + li][lg * 8]);
        #pragma unroll
        for (int nj = 0; nj < 4; ++nj)
            bfr[nj] = *reinterpret_cast<const bf16x8*>(&Bs[wc * 64 + nj * 16 + li][lg * 8]);
        #pragma unroll
        for (int mi = 0; mi < 4; ++mi)
            #pragma unroll
            for (int nj = 0; nj < 4; ++nj)
                acc[mi][nj] = __builtin_amdgcn_mfma_f32_16x16x32_bf16(
                    af[mi], bfr[nj], acc[mi][nj], 0, 0, 0);
        __syncthreads();
    }

    int brow[4][4], srow[4][4];
    #pragma unroll
    for (int mi = 0; mi < 4; ++mi)
        #pragma unroll
        for (int r = 0; r < 4; ++r) {
            int m = m0 + wr * 64 + mi * 16 + lg * 4 + r;
            int mm = (m < MROWS) ? m : (MROWS - 1);
            int bb = mm / SEQ;
            brow[mi][r] = bb;
            srow[mi][r] = mm - bb * SEQ;
        }

    #pragma unroll
    for (int nj = 0; nj < 4; ++nj) {
        const int n = n0 + wc * 64 + nj * 16 + li;
        const int which = n / EMBED;
        const int nh = n - which * EMBED;
        const int h = nh >> 6, d = nh & 63;
        unsigned short* outp = (which == 0) ? qout : (which == 1) ? kout : vout;
        const float mul = (which == 0) ? SCALE : 1.0f;
        const float bn = bias[n];
        const bool dorope = which < 2;
        const float sgn = (d & 1) ? 1.f : -1.f;
        #pragma unroll
        for (int mi = 0; mi < 4; ++mi)
            #pragma unroll
            for (int r = 0; r < 4; ++r) {
                const int m = m0 + wr * 64 + mi * 16 + lg * 4 + r;
                float v = acc[mi][nj][r] + bn;
                float pv = __shfl_xor(v, 1, 64);
                if (m < MROWS) {
                    const int bb = brow[mi][r], s = srow[mi][r];
                    if (dorope && s >= 1) {
                        const int p = s - 1;
                        v = v * cosT[(p << 6) + d] + sgn * pv * sinT[(p << 6) + d];
                    }
                    outp[((long)(bb * NHEADS + h) * SEQ + s) * HDIM + d] = f2bf(v * mul);
                }
            }
    }
}

// ---------------- Flash attention, bf16 MFMA, rel-pos bias via linear codes ----------------
__global__ __launch_bounds__(256)
void attn_mfma_kernel(const unsigned short* __restrict__ qg,
                      const unsigned short* __restrict__ kg,
                      const unsigned short* __restrict__ vg,
                      const float* __restrict__ btT,
                      const unsigned char* __restrict__ mask,
                      unsigned short* __restrict__ ctx)
{
    __shared__ unsigned short Qs[64][64];
    __shared__ unsigned short Ks[64][64];
    __shared__ unsigned short Vts[64][64];   // [d][k], swizzle col ^= ((row^(row>>3))&7)<<3
    __shared__ unsigned short Ps[4][16][64];

    const int q0 = blockIdx.x * 64;
    const int bh = (int)blockIdx.y;
    const int b = bh / NHEADS, h = bh % NHEADS;
    const int tid = threadIdx.x;
    const int w = tid >> 6;
    const int lane = tid & 63;
    const int lg = lane >> 4;
    const int li = lane & 15;

    const unsigned short* qbase = qg + (long)bh * (SEQ * HDIM);
    const unsigned short* kbase = kg + (long)bh * (SEQ * HDIM);
    const unsigned short* vbase = vg + (long)bh * (SEQ * HDIM);
    const unsigned char* maskp = mask + b * SEQ;
    const float* btTh = btT + h * BT_N;

    // ---- stage Q via gld16, pre-swizzled source (LDS gets Qs[r][c^((r&7)<<3)]) ----
    #pragma unroll
    for (int c = 0; c < 2; ++c) {
        const int idx = c * 256 + tid;
        const int r = idx >> 3, col8 = (idx & 7) << 3;
        int qi = q0 + r; if (qi > SEQ - 1) qi = SEQ - 1;   // clamped tail, rows unused
        gld16(&qbase[(long)qi * HDIM + (col8 ^ ((r & 7) << 3))], &Qs[0][0] + idx * 8);
    }

    // per-row bias q-codes (+1984 folded); clamped tail rows produce in-bounds garbage
    int qcode[4]; bool qhasb[4];
    #pragma unroll
    for (int r = 0; r < 4; ++r) {
        const int qi = q0 + (w << 4) + (lg << 2) + r;
        qhasb[r] = (qi >= 1);
        int qp = qi - 1; if (qp < 0) qp = 0; if (qp > 1023) qp = 1023;
        qcode[r] = (qp >> 5) * 63 + (qp & 31) + 1984;
    }

    float m_r[4], l_r[4];
    f32x4 acco[4];
    #pragma unroll
    for (int r = 0; r < 4; ++r) { m_r[r] = -1e30f; l_r[r] = 0.f; }
    #pragma unroll
    for (int j = 0; j < 4; ++j) acco[j] = (f32x4){0.f, 0.f, 0.f, 0.f};

    for (int kt = 0; kt < 17; ++kt) {
        const int k0 = kt * 64;
        __syncthreads();   // prev iter reads done (also drains Q gld16 on iter 0)

        // ---- stage K via gld16 (pre-swizzled source, rows clamped -> finite, masked) ----
        #pragma unroll
        for (int c = 0; c < 2; ++c) {
            const int idx = c * 256 + tid;
            const int r = idx >> 3, col8 = (idx & 7) << 3;
            int ki = k0 + r; if (ki > SEQ - 1) ki = SEQ - 1;
            gld16(&kbase[(long)ki * HDIM + (col8 ^ ((r & 7) << 3))], &Ks[0][0] + idx * 8);
        }
        // ---- stage V^T manually, conflict-free swizzle; zero-fill tail (PV safety) ----
        #pragma unroll
        for (int c = 0; c < 2; ++c) {
            const int i = c * 256 + tid;
            const int r = i >> 3, c8 = (i & 7) << 3;
            const int ki = k0 + r;
            int4 vv = make_int4(0, 0, 0, 0);
            if (ki < SEQ) vv = *reinterpret_cast<const int4*>(&vbase[(long)ki * HDIM + c8]);
            union { int4 v; unsigned short u[8]; } t; t.v = vv;
            const int cb3 = c8 >> 3;
            #pragma unroll
            for (int e = 0; e < 8; ++e)
                Vts[c8 + e][r ^ (((e ^ cb3) & 7) << 3)] = t.u[e];
        }
        __syncthreads();

        // ---- QK^T ----
        f32x4 accs[4];
        #pragma unroll
        for (int j = 0; j < 4; ++j) accs[j] = (f32x4){0.f, 0.f, 0.f, 0.f};
        #pragma unroll
        for (int dk = 0; dk < 64; dk += 32) {
            const int cb = dk + (lg << 3);
            const int qrow = (w << 4) + li;
            bf16x8 a = *reinterpret_cast<const bf16x8*>(&Qs[qrow][cb ^ ((li & 7) << 3)]);
            #pragma unroll
            for (int j = 0; j < 4; ++j) {
                const int krow = (j << 4) + li;
                bf16x8 bfrag = *reinterpret_cast<const bf16x8*>(&Ks[krow][cb ^ ((li & 7) << 3)]);
                accs[j] = __builtin_amdgcn_mfma_f32_16x16x32_bf16(a, bfrag, accs[j], 0, 0, 0);
            }
        }

        // ---- per-j k-side codes, mask hoisted ----
        int kcode[4]; bool kdead[4], khasb[4];
        #pragma unroll
        for (int j = 0; j < 4; ++j) {
            const int ki = k0 + (j << 4) + li;
            const int kic = (ki > SEQ - 1) ? (SEQ - 1) : ki;
            kdead[j] = (ki >= SEQ) || (maskp[kic] != 0);
            khasb[j] = (ki >= 1);
            int kp = ki - 1; if (kp < 0) kp = 0; if (kp > 1023) kp = 1023;
            kcode[j] = (kp >> 5) * 63 + (kp & 31);
        }

        // ---- bias + mask + online softmax ----
        float alpha[4];
        #pragma unroll
        for (int r = 0; r < 4; ++r) {
            const int rl = (lg << 2) + r;
            float sr[4];
            #pragma unroll
            for (int j = 0; j < 4; ++j) {
                float s = accs[j][r];
                const float bv = btTh[qcode[r] - kcode[j]];   // always in-bounds
                if (qhasb[r] && khasb[j]) s += bv;
                if (kdead[j]) s = -1e30f;
                sr[j] = s;
            }
            float mx = fmaxf(fmaxf(sr[0], sr[1]), fmaxf(sr[2], sr[3]));
            #pragma unroll
            for (int off = 1; off < 16; off <<= 1)
                mx = fmaxf(mx, __shfl_xor(mx, off, 64));
            float mnew = fmaxf(m_r[r], mx);
            alpha[r] = __expf(m_r[r] - mnew);
            float rs = 0.f;
            #pragma unroll
            for (int j = 0; j < 4; ++j) {
                float p = __expf(sr[j] - mnew);
                rs += p;
                Ps[w][rl][((j << 4) + li) ^ ((rl & 7) << 3)] = f2bf(p);
            }
            #pragma unroll
            for (int off = 1; off < 16; off <<= 1)
                rs += __shfl_xor(rs, off, 64);
            l_r[r] = l_r[r] * alpha[r] + rs;
            m_r[r] = mnew;
        }

        #pragma unroll
        for (int j = 0; j < 4; ++j)
            #pragma unroll
            for (int r = 0; r < 4; ++r)
                acco[j][r] *= alpha[r];

        // ---- PV (Vts read uses the write-side involution) ----
        #pragma unroll
        for (int kk = 0; kk < 64; kk += 32) {
            const int cb = kk + (lg << 3);
            bf16x8 a = *reinterpret_cast<const bf16x8*>(&Ps[w][li][cb ^ ((li & 7) << 3)]);
            #pragma unroll
            for (int j = 0; j < 4; ++j) {
                const int drow = (j << 4) + li;
                const int sv = ((drow ^ (drow >> 3)) & 7) << 3;
                bf16x8 bfrag = *reinterpret_cast<const bf16x8*>(&Vts[drow][cb ^ sv]);
                acco[j] = __builtin_amdgcn_mfma_f32_16x16x32_bf16(a, bfrag, acco[j], 0, 0, 0);
            }
        }
    }

    #pragma unroll
    for (int r = 0; r < 4; ++r) {
        const int rl = (lg << 2) + r;
        const int qi = q0 + (w << 4) + rl;
        if (qi < SEQ) {
            const float inv = 1.0f / l_r[r];
            #pragma unroll
            for (int j = 0; j < 4; ++j)
                ctx[(long)(b * SEQ + qi) * EMBED + h * HDIM + (j << 4) + li] =
                    f2bf(acco[j][r] * inv);
        }
    }
}

// ---------------- Output projection (bf16 MFMA): out = ctx @ proj_w^T + b ----------------
__global__ __launch_bounds__(256)
void proj_mfma_kernel(const unsigned short* __restrict__ ctxbf,
                      const unsigned short* __restrict__ pwbf,
                      const float* __restrict__ bias, float* __restrict__ out)
{
    __shared__ unsigned short As[128][32];
    __shared__ unsigned short Bs[128][32];
    const int m0 = blockIdx.x * 128;
    const int n0 = blockIdx.y * 128;
    const int tid = threadIdx.x;
    const int w = tid >> 6, lane = tid & 63;
    const int li = lane & 15, lg = lane >> 4;
    const int wr = w >> 1, wc = w & 1;

    f32x4 acc[4][4];
    #pragma unroll
    for (int mi = 0; mi < 4; ++mi)
        #pragma unroll
        for (int nj = 0; nj < 4; ++nj) acc[mi][nj] = (f32x4){0.f, 0.f, 0.f, 0.f};

    for (int kt = 0; kt < 24; ++kt) {
        const int k0 = kt << 5;
        #pragma unroll
        for (int c = 0; c < 2; ++c) {
            const int idx = c * 256 + tid;
            const int row = idx >> 2, slot = idx & 3;
            int grow = m0 + row; if (grow > MROWS - 1) grow = MROWS - 1;
            gld16(&ctxbf[(long)grow * EMBED + k0 + slot * 8], &As[0][0] + idx * 8);
            gld16(&pwbf[(long)(n0 + row) * EMBED + k0 + slot * 8], &Bs[0][0] + idx * 8);
        }
        __syncthreads();

        bf16x8 af[4], bfr[4];
        #pragma unroll
        for (int mi = 0; mi < 4; ++mi)
            af[mi] = *reinterpret_cast<const bf16x8*>(&As[wr * 64 + mi * 16 + li][lg * 8]);
        #pragma unroll
        for (int nj = 0; nj < 4; ++nj)
            bfr[nj] = *reinterpret_cast<const bf16x8*>(&Bs[wc * 64 + nj * 16 + li][lg * 8]);
        #pragma unroll
        for (int mi = 0; mi < 4; ++mi)
            #pragma unroll
            for (int nj = 0; nj < 4; ++nj)
                acc[mi][nj] = __builtin_amdgcn_mfma_f32_16x16x32_bf16(
                    af[mi], bfr[nj], acc[mi][nj], 0, 0, 0);
        __syncthreads();
    }

    #pragma unroll
    for (int nj = 0; nj < 4; ++nj) {
        const int n = n0 + wc * 64 + nj * 16 + li;
        const float bn = bias[n];
        #pragma unroll
        for (int mi = 0; mi < 4; ++mi)
            #pragma unroll
            for (int r = 0; r < 4; ++r) {
                const int m = m0 + wr * 64 + mi * 16 + lg * 4 + r;
                if (m < MROWS)
                    out[(long)m * EMBED + n] = acc[mi][nj][r] + bn;
            }
    }
}

extern "C" void kernel_launch(void* const* d_in, const int* in_sizes, int n_in,
                              void* d_out, int out_size, void* d_ws, size_t ws_size,
                              hipStream_t stream) {
    const float* x       = (const float*)d_in[0];
    const float* qkv_w   = (const float*)d_in[1];
    const float* qkv_b   = (const float*)d_in[2];
    const float* proj_w  = (const float*)d_in[3];
    const float* proj_b  = (const float*)d_in[4];
    const float* rel_bt  = (const float*)d_in[5];
    const unsigned char* kmask = (const unsigned char*)d_in[6];
    float* out = (float*)d_out;

    unsigned short* qbuf  = (unsigned short*)d_ws;
    unsigned short* kbuf  = qbuf + QKV_ELEMS;
    unsigned short* vbuf  = kbuf + QKV_ELEMS;
    unsigned short* ctxbf = vbuf + QKV_ELEMS;
    unsigned short* xbf   = ctxbf + QKV_ELEMS;
    unsigned short* wbf   = xbf + QKV_ELEMS;            // 2304*768
    unsigned short* pwbf  = wbf + QKV_N * EMBED;        // 768*768
    float* cosT = (float*)(pwbf + EMBED * EMBED);
    float* sinT = cosT + 1024 * HDIM;
    float* btT  = sinT + 1024 * HDIM;                   // 12*3969 fp32

    const int nx = MROWS * EMBED / 4;
    const int nw = QKV_N * EMBED / 4;
    const int np = EMBED * EMBED / 4;
    f2bf_kernel<<<(nx + 255) / 256, 256, 0, stream>>>(x, xbf, nx);
    f2bf_kernel<<<(nw + 255) / 256, 256, 0, stream>>>(qkv_w, wbf, nw);
    f2bf_kernel<<<(np + 255) / 256, 256, 0, stream>>>(proj_w, pwbf, np);
    rope_table_kernel<<<1024, 64, 0, stream>>>(cosT, sinT);
    bt_transpose_kernel<<<dim3((BT_N + 255) / 256, NHEADS), 256, 0, stream>>>(rel_bt, btT);

    qkv_mfma_kernel<<<dim3((MROWS + 127) / 128, QKV_N / 128), 256, 0, stream>>>(
        xbf, wbf, qkv_b, cosT, sinT, qbuf, kbuf, vbuf);
    attn_mfma_kernel<<<dim3((SEQ + 63) / 64, BHCOUNT), 256, 0, stream>>>(
        qbuf, kbuf, vbuf, btT, kmask, ctxbf);
    proj_mfma_kernel<<<dim3((MROWS + 127) / 128, EMBED / 128), 256, 0, stream>>>(
        ctxbf, pwbf, proj_b, out);
}

// Round 5
// 286.586 us; speedup vs baseline: 8.7797x; 1.1962x over previous
//
#include <hip/hip_runtime.h>
#include <math.h>

#define EMBED 768
#define NHEADS 12
#define HDIM 64
#define SEQ 1025
#define NBATCH 8
#define BHCOUNT (NBATCH*NHEADS)   // 96
#define MROWS (NBATCH*SEQ)        // 8200
#define QKV_N (3*EMBED)           // 2304
#define QKV_ELEMS (BHCOUNT*SEQ*HDIM)  // 6,297,600 elems (== MROWS*EMBED)
#define BT_N 3969                 // (2*32-1)^2
#define MASKPAD 1088              // 4-aligned padded mask row
// q pre-scale = 0.125 * log2(e): softmax runs in exp2 domain
#define QMUL 0.1803368801111204f
#define LOG2E 1.4426950408889634f

typedef __attribute__((ext_vector_type(8))) short bf16x8;
typedef __attribute__((ext_vector_type(4))) float f32x4;

static __device__ inline unsigned short f2bf(float f) {
    unsigned u = __float_as_uint(f);
    unsigned r = (u + 0x7FFF + ((u >> 16) & 1)) >> 16;   // RNE
    return (unsigned short)r;
}

// async global->LDS, 16B per lane, linear LDS dest (wave-uniform base + lane*16)
static __device__ inline void gld16(const unsigned short* g, unsigned short* l) {
    __builtin_amdgcn_global_load_lds(
        (const __attribute__((address_space(1))) unsigned int*)g,
        (__attribute__((address_space(3))) unsigned int*)l,
        16, 0, 0);
}

// ---------------- fp32 -> bf16 convert (vectorized, n % 4 == 0) ----------------
__global__ __launch_bounds__(256)
void f2bf_kernel(const float* __restrict__ src, unsigned short* __restrict__ dst, int n4) {
    int i = blockIdx.x * 256 + threadIdx.x;
    if (i < n4) {
        float4 v = *reinterpret_cast<const float4*>(&src[i << 2]);
        ushort4 o;
        o.x = f2bf(v.x); o.y = f2bf(v.y); o.z = f2bf(v.z); o.w = f2bf(v.w);
        *reinterpret_cast<ushort4*>(&dst[i << 2]) = o;
    }
}

// ---------------- RoPE tables: cos/sin [1024][64] ----------------
__global__ void rope_table_kernel(float* __restrict__ cosT, float* __restrict__ sinT) {
    int s = blockIdx.x;
    int d = threadIdx.x;
    int pos = (d < 32) ? (s >> 5) : (s & 31);
    int j = (d & 31) >> 1;
    float ang = (float)pos * expf(-(float)j * 0.5756462732485115f);
    cosT[(s << 6) + d] = cosf(ang);
    sinT[(s << 6) + d] = sinf(ang);
}

// ---------------- bias table transpose (scaled by log2e): btT[h][3969] ----------------
__global__ __launch_bounds__(256)
void bt_transpose_kernel(const float* __restrict__ bt, float* __restrict__ btT) {
    int e = blockIdx.x * 256 + threadIdx.x;
    int h = blockIdx.y;
    if (e < BT_N) btT[h * BT_N + e] = bt[e * NHEADS + h] * LOG2E;
}

// ---------------- mask pad: [B][1088], zero-filled tail, 4-aligned rows ----------------
__global__ __launch_bounds__(256)
void mask_pad_kernel(const unsigned char* __restrict__ m, unsigned char* __restrict__ mp) {
    int b = blockIdx.x;
    for (int i = threadIdx.x; i < MASKPAD; i += 256)
        mp[b * MASKPAD + i] = (i < SEQ) ? m[b * SEQ + i] : (unsigned char)0;
}

// ---------------- QKV GEMM (bf16 MFMA, m97 structure) ----------------
__global__ __launch_bounds__(256)
void qkv_mfma_kernel(const unsigned short* __restrict__ xbf,
                     const unsigned short* __restrict__ wbf,
                     const float* __restrict__ bias,
                     const float* __restrict__ cosT, const float* __restrict__ sinT,
                     unsigned short* __restrict__ qout, unsigned short* __restrict__ kout,
                     unsigned short* __restrict__ vout)
{
    __shared__ unsigned short As[128][32];
    __shared__ unsigned short Bs[128][32];
    const int m0 = blockIdx.x * 128;
    const int n0 = blockIdx.y * 128;
    const int tid = threadIdx.x;
    const int w = tid >> 6, lane = tid & 63;
    const int li = lane & 15, lg = lane >> 4;
    const int wr = w >> 1, wc = w & 1;

    f32x4 acc[4][4];
    #pragma unroll
    for (int mi = 0; mi < 4; ++mi)
        #pragma unroll
        for (int nj = 0; nj < 4; ++nj) acc[mi][nj] = (f32x4){0.f, 0.f, 0.f, 0.f};

    for (int kt = 0; kt < 24; ++kt) {
        const int k0 = kt << 5;
        #pragma unroll
        for (int c = 0; c < 2; ++c) {
            const int idx = c * 256 + tid;       // 0..511
            const int row = idx >> 2, slot = idx & 3;
            int grow = m0 + row; if (grow > MROWS - 1) grow = MROWS - 1;
            gld16(&xbf[(long)grow * EMBED + k0 + slot * 8], &As[0][0] + idx * 8);
            gld16(&wbf[(long)(n0 + row) * EMBED + k0 + slot * 8], &Bs[0][0] + idx * 8);
        }
        __syncthreads();

        bf16x8 af[4], bfr[4];
        #pragma unroll
        for (int mi = 0; mi < 4; ++mi)
            af[mi] = *reinterpret_cast<const bf16x8*>(&As[wr * 64 + mi * 16 + li][lg * 8]);
        #pragma unroll
        for (int nj = 0; nj < 4; ++nj)
            bfr[nj] = *reinterpret_cast<const bf16x8*>(&Bs[wc * 64 + nj * 16 + li][lg * 8]);
        __builtin_amdgcn_s_setprio(1);
        #pragma unroll
        for (int mi = 0; mi < 4; ++mi)
            #pragma unroll
            for (int nj = 0; nj < 4; ++nj)
                acc[mi][nj] = __builtin_amdgcn_mfma_f32_16x16x32_bf16(
                    af[mi], bfr[nj], acc[mi][nj], 0, 0, 0);
        __builtin_amdgcn_s_setprio(0);
        __syncthreads();
    }

    int brow[4][4], srow[4][4];
    #pragma unroll
    for (int mi = 0; mi < 4; ++mi)
        #pragma unroll
        for (int r = 0; r < 4; ++r) {
            int m = m0 + wr * 64 + mi * 16 + lg * 4 + r;
            int mm = (m < MROWS) ? m : (MROWS - 1);
            int bb = mm / SEQ;
            brow[mi][r] = bb;
            srow[mi][r] = mm - bb * SEQ;
        }

    #pragma unroll
    for (int nj = 0; nj < 4; ++nj) {
        const int n = n0 + wc * 64 + nj * 16 + li;
        const int which = n / EMBED;
        const int nh = n - which * EMBED;
        const int h = nh >> 6, d = nh & 63;
        unsigned short* outp = (which == 0) ? qout : (which == 1) ? kout : vout;
        const float mul = (which == 0) ? QMUL : 1.0f;
        const float bn = bias[n];
        const bool dorope = which < 2;
        const float sgn = (d & 1) ? 1.f : -1.f;
        #pragma unroll
        for (int mi = 0; mi < 4; ++mi)
            #pragma unroll
            for (int r = 0; r < 4; ++r) {
                const int m = m0 + wr * 64 + mi * 16 + lg * 4 + r;
                float v = acc[mi][nj][r] + bn;
                float pv = __shfl_xor(v, 1, 64);
                if (m < MROWS) {
                    const int bb = brow[mi][r], s = srow[mi][r];
                    if (dorope && s >= 1) {
                        const int p = s - 1;
                        v = v * cosT[(p << 6) + d] + sgn * pv * sinT[(p << 6) + d];
                    }
                    outp[((long)(bb * NHEADS + h) * SEQ + s) * HDIM + d] = f2bf(v * mul);
                }
            }
    }
}

// ---------------- Flash attention: swapped QK^T (S^T = K·Q^T), in-reg row softmax ----------------
// grid (17, 96), block 256 (4 waves). Wave w owns q rows q0+w*16 .. +15; lane li = its q row.
// S^T C-layout: accs[j][r] = S[q = w*16+li][kv = j*16 + lg*4 + r].
__global__ __launch_bounds__(256)
void attn_mfma_kernel(const unsigned short* __restrict__ qg,
                      const unsigned short* __restrict__ kg,
                      const unsigned short* __restrict__ vg,
                      const float* __restrict__ btT,
                      const unsigned char* __restrict__ maskpad,
                      unsigned short* __restrict__ ctx)
{
    __shared__ unsigned short QPs[64][64];   // Q staging, then per-wave P strips (rows w*16..)
    __shared__ unsigned short Ks[64][64];    // [kv][d], swizzle col ^= (row&7)<<3
    __shared__ unsigned short Vts[64][64];   // [d][kv], swizzle col ^= ((row^(row>>3))&7)<<3

    const int q0 = blockIdx.x * 64;
    const int bh = (int)blockIdx.y;
    const int b = bh / NHEADS, h = bh % NHEADS;
    const int tid = threadIdx.x;
    const int w = tid >> 6;
    const int lane = tid & 63;
    const int lg = lane >> 4;
    const int li = lane & 15;
    const int qrow = (w << 4) + li;          // this lane's q row (local)
    const int swzr = (li & 7) << 3;          // row-swizzle for QPs/Ks rows ≡ li (mod 8)

    const unsigned short* qbase = qg + (long)bh * (SEQ * HDIM);
    const unsigned short* kbase = kg + (long)bh * (SEQ * HDIM);
    const unsigned short* vbase = vg + (long)bh * (SEQ * HDIM);
    const unsigned char* maskp = maskpad + b * MASKPAD;
    const float* btTh = btT + h * BT_N;

    // ---- stage Q via gld16, pre-swizzled source ----
    #pragma unroll
    for (int c = 0; c < 2; ++c) {
        const int idx = c * 256 + tid;
        const int r = idx >> 3, col8 = (idx & 7) << 3;
        int qi = q0 + r; if (qi > SEQ - 1) qi = SEQ - 1;
        gld16(&qbase[(long)qi * HDIM + (col8 ^ ((r & 7) << 3))], &QPs[0][0] + idx * 8);
    }
    __syncthreads();

    // ---- hoist Q fragments (B-operand, constant over j AND kt) ----
    bf16x8 qf[2];
    #pragma unroll
    for (int dk = 0; dk < 2; ++dk)
        qf[dk] = *reinterpret_cast<const bf16x8*>(&QPs[qrow][(dk * 32 + (lg << 3)) ^ swzr]);

    // per-lane q-side bias code (+1984 folded); bq=0 kills bias for the CLS q-row
    const int qi_l = q0 + qrow;
    const float bq = (qi_l >= 1) ? 1.0f : 0.0f;
    int qp = qi_l - 1; if (qp < 0) qp = 0; if (qp > 1023) qp = 1023;
    const int qcode = (qp >> 5) * 63 + (qp & 31) + 1984;

    float m_l = -1e30f, l_l = 0.f;
    f32x4 acco[4];
    #pragma unroll
    for (int j = 0; j < 4; ++j) acco[j] = (f32x4){0.f, 0.f, 0.f, 0.f};

    int kc[4][4];            // k-side bias codes for kv = j*16 + lg*4 + r
    for (int kt = 0; kt < 17; ++kt) {
        const int k0 = kt * 64;
        __syncthreads();   // prev-tile Ks/Vts reads done (iter 0: after Q hoist)

        // ---- stage K via gld16 (pre-swizzled source, clamped tail) ----
        #pragma unroll
        for (int c = 0; c < 2; ++c) {
            const int idx = c * 256 + tid;
            const int r = idx >> 3, col8 = (idx & 7) << 3;
            int ki = k0 + r; if (ki > SEQ - 1) ki = SEQ - 1;
            gld16(&kbase[(long)ki * HDIM + (col8 ^ ((r & 7) << 3))], &Ks[0][0] + idx * 8);
        }
        // ---- stage V^T manually (conflict-free swizzle, zero tail) ----
        #pragma unroll
        for (int c = 0; c < 2; ++c) {
            const int i = c * 256 + tid;
            const int r = i >> 3, c8 = (i & 7) << 3;
            const int ki = k0 + r;
            int4 vv = make_int4(0, 0, 0, 0);
            if (ki < SEQ) vv = *reinterpret_cast<const int4*>(&vbase[(long)ki * HDIM + c8]);
            union { int4 v; unsigned short u[8]; } t; t.v = vv;
            const int cb3 = c8 >> 3;
            #pragma unroll
            for (int e = 0; e < 8; ++e)
                Vts[c8 + e][r ^ (((e ^ cb3) & 7) << 3)] = t.u[e];
        }
        __syncthreads();

        // ---- S^T = K · Q^T : accs[j] covers kv rows j*16..j*16+15, q col = li ----
        f32x4 accs[4];
        #pragma unroll
        for (int j = 0; j < 4; ++j) accs[j] = (f32x4){0.f, 0.f, 0.f, 0.f};
        __builtin_amdgcn_s_setprio(1);
        #pragma unroll
        for (int dk = 0; dk < 2; ++dk) {
            const int cb = dk * 32 + (lg << 3);
            #pragma unroll
            for (int j = 0; j < 4; ++j) {
                bf16x8 kf = *reinterpret_cast<const bf16x8*>(&Ks[(j << 4) + li][cb ^ swzr]);
                accs[j] = __builtin_amdgcn_mfma_f32_16x16x32_bf16(kf, qf[dk], accs[j], 0, 0, 0);
            }
        }
        __builtin_amdgcn_s_setprio(0);

        // ---- k-side codes + mask: fast incremental path for interior tiles ----
        unsigned int b4[4];   // byte r nonzero => kv dead
        if (kt >= 1 && kt <= 15) {
            #pragma unroll
            for (int j = 0; j < 4; ++j) {
                b4[j] = *reinterpret_cast<const unsigned int*>(&maskp[k0 + (j << 4) + (lg << 2)]);
                #pragma unroll
                for (int r = 0; r < 4; ++r) kc[j][r] += 126;
            }
        } else {
            #pragma unroll
            for (int j = 0; j < 4; ++j) {
                unsigned int bb = 0;
                #pragma unroll
                for (int r = 0; r < 4; ++r) {
                    const int ki = k0 + (j << 4) + (lg << 2) + r;
                    unsigned int dead = (ki >= SEQ) ? 1u : (unsigned int)maskp[ki];
                    bb |= (dead ? 1u : 0u) << (r * 8);
                    int kp = ki - 1; if (kp < 0) kp = 0; if (kp > 1023) kp = 1023;
                    kc[j][r] = (kp >> 5) * 63 + (kp & 31);
                }
                b4[j] = bb;
            }
        }

        // ---- bias + mask (scores in exp2 domain already) ----
        float sv[4][4];
        #pragma unroll
        for (int j = 0; j < 4; ++j)
            #pragma unroll
            for (int r = 0; r < 4; ++r) {
                float s = accs[j][r] + btTh[qcode - kc[j][r]] * bq;
                sv[j][r] = ((b4[j] >> (r * 8)) & 0xFF) ? -1e30f : s;
            }
        if (kt == 0 && lg == 0)   // kv==0 (CLS col): no bias for any q
            sv[0][0] = (b4[0] & 0xFF) ? -1e30f : accs[0][0];

        // ---- in-register row softmax (row = this lane's q) ----
        float mx = sv[0][0];
        #pragma unroll
        for (int j = 0; j < 4; ++j)
            #pragma unroll
            for (int r = 0; r < 4; ++r) mx = fmaxf(mx, sv[j][r]);
        mx = fmaxf(mx, __shfl_xor(mx, 16, 64));
        mx = fmaxf(mx, __shfl_xor(mx, 32, 64));
        const float mnew = fmaxf(m_l, mx);
        const float alpha = __builtin_amdgcn_exp2f(m_l - mnew);
        float rs = 0.f;
        #pragma unroll
        for (int j = 0; j < 4; ++j) {
            float p0 = __builtin_amdgcn_exp2f(sv[j][0] - mnew);
            float p1 = __builtin_amdgcn_exp2f(sv[j][1] - mnew);
            float p2 = __builtin_amdgcn_exp2f(sv[j][2] - mnew);
            float p3 = __builtin_amdgcn_exp2f(sv[j][3] - mnew);
            rs += (p0 + p1) + (p2 + p3);
            ushort4 pk;
            pk.x = f2bf(p0); pk.y = f2bf(p1); pk.z = f2bf(p2); pk.w = f2bf(p3);
            *reinterpret_cast<ushort4*>(
                &QPs[qrow][((j << 4) + (lg << 2)) ^ swzr]) = pk;   // P[q=li][kv], b64 write
        }
        rs += __shfl_xor(rs, 16, 64);
        rs += __shfl_xor(rs, 32, 64);
        l_l = l_l * alpha + rs;
        m_l = mnew;

        // ---- broadcast alpha to O's row layout (row q = lg*4+r) and rescale ----
        float al[4];
        #pragma unroll
        for (int r = 0; r < 4; ++r) al[r] = __shfl(alpha, (lg << 2) + r, 64);
        #pragma unroll
        for (int j = 0; j < 4; ++j)
            #pragma unroll
            for (int r = 0; r < 4; ++r) acco[j][r] *= al[r];

        // ---- PV: O += P · V  (A = P from wave-private strip, B = V^T) ----
        __builtin_amdgcn_s_setprio(1);
        #pragma unroll
        for (int kk = 0; kk < 2; ++kk) {
            const int cb = kk * 32 + (lg << 3);
            bf16x8 pf = *reinterpret_cast<const bf16x8*>(&QPs[qrow][cb ^ swzr]);
            #pragma unroll
            for (int j = 0; j < 4; ++j) {
                const int drow = (j << 4) + li;
                const int sv2 = ((drow ^ (drow >> 3)) & 7) << 3;
                bf16x8 vf = *reinterpret_cast<const bf16x8*>(&Vts[drow][cb ^ sv2]);
                acco[j] = __builtin_amdgcn_mfma_f32_16x16x32_bf16(pf, vf, acco[j], 0, 0, 0);
            }
        }
        __builtin_amdgcn_s_setprio(0);
    }

    // ---- epilogue: O rows are q = lg*4+r; fetch l via bpermute ----
    float lb[4];
    #pragma unroll
    for (int r = 0; r < 4; ++r) lb[r] = __shfl(l_l, (lg << 2) + r, 64);
    #pragma unroll
    for (int r = 0; r < 4; ++r) {
        const int rl = (lg << 2) + r;
        const int qi = q0 + (w << 4) + rl;
        if (qi < SEQ) {
            const float inv = 1.0f / lb[r];
            #pragma unroll
            for (int j = 0; j < 4; ++j)
                ctx[(long)(b * SEQ + qi) * EMBED + h * HDIM + (j << 4) + li] =
                    f2bf(acco[j][r] * inv);
        }
    }
}

// ---------------- Output projection (bf16 MFMA): out = ctx @ proj_w^T + b ----------------
__global__ __launch_bounds__(256)
void proj_mfma_kernel(const unsigned short* __restrict__ ctxbf,
                      const unsigned short* __restrict__ pwbf,
                      const float* __restrict__ bias, float* __restrict__ out)
{
    __shared__ unsigned short As[128][32];
    __shared__ unsigned short Bs[128][32];
    const int m0 = blockIdx.x * 128;
    const int n0 = blockIdx.y * 128;
    const int tid = threadIdx.x;
    const int w = tid >> 6, lane = tid & 63;
    const int li = lane & 15, lg = lane >> 4;
    const int wr = w >> 1, wc = w & 1;

    f32x4 acc[4][4];
    #pragma unroll
    for (int mi = 0; mi < 4; ++mi)
        #pragma unroll
        for (int nj = 0; nj < 4; ++nj) acc[mi][nj] = (f32x4){0.f, 0.f, 0.f, 0.f};

    for (int kt = 0; kt < 24; ++kt) {
        const int k0 = kt << 5;
        #pragma unroll
        for (int c = 0; c < 2; ++c) {
            const int idx = c * 256 + tid;
            const int row = idx >> 2, slot = idx & 3;
            int grow = m0 + row; if (grow > MROWS - 1) grow = MROWS - 1;
            gld16(&ctxbf[(long)grow * EMBED + k0 + slot * 8], &As[0][0] + idx * 8);
            gld16(&pwbf[(long)(n0 + row) * EMBED + k0 + slot * 8], &Bs[0][0] + idx * 8);
        }
        __syncthreads();

        bf16x8 af[4], bfr[4];
        #pragma unroll
        for (int mi = 0; mi < 4; ++mi)
            af[mi] = *reinterpret_cast<const bf16x8*>(&As[wr * 64 + mi * 16 + li][lg * 8]);
        #pragma unroll
        for (int nj = 0; nj < 4; ++nj)
            bfr[nj] = *reinterpret_cast<const bf16x8*>(&Bs[wc * 64 + nj * 16 + li][lg * 8]);
        __builtin_amdgcn_s_setprio(1);
        #pragma unroll
        for (int mi = 0; mi < 4; ++mi)
            #pragma unroll
            for (int nj = 0; nj < 4; ++nj)
                acc[mi][nj] = __builtin_amdgcn_mfma_f32_16x16x32_bf16(
                    af[mi], bfr[nj], acc[mi][nj], 0, 0, 0);
        __builtin_amdgcn_s_setprio(0);
        __syncthreads();
    }

    #pragma unroll
    for (int nj = 0; nj < 4; ++nj) {
        const int n = n0 + wc * 64 + nj * 16 + li;
        const float bn = bias[n];
        #pragma unroll
        for (int mi = 0; mi < 4; ++mi)
            #pragma unroll
            for (int r = 0; r < 4; ++r) {
                const int m = m0 + wr * 64 + mi * 16 + lg * 4 + r;
                if (m < MROWS)
                    out[(long)m * EMBED + n] = acc[mi][nj][r] + bn;
            }
    }
}

extern "C" void kernel_launch(void* const* d_in, const int* in_sizes, int n_in,
                              void* d_out, int out_size, void* d_ws, size_t ws_size,
                              hipStream_t stream) {
    const float* x       = (const float*)d_in[0];
    const float* qkv_w   = (const float*)d_in[1];
    const float* qkv_b   = (const float*)d_in[2];
    const float* proj_w  = (const float*)d_in[3];
    const float* proj_b  = (const float*)d_in[4];
    const float* rel_bt  = (const float*)d_in[5];
    const unsigned char* kmask = (const unsigned char*)d_in[6];
    float* out = (float*)d_out;

    unsigned short* qbuf  = (unsigned short*)d_ws;
    unsigned short* kbuf  = qbuf + QKV_ELEMS;
    unsigned short* vbuf  = kbuf + QKV_ELEMS;
    unsigned short* ctxbf = vbuf + QKV_ELEMS;
    unsigned short* xbf   = ctxbf + QKV_ELEMS;
    unsigned short* wbf   = xbf + QKV_ELEMS;            // 2304*768
    unsigned short* pwbf  = wbf + QKV_N * EMBED;        // 768*768
    float* cosT = (float*)(pwbf + EMBED * EMBED);
    float* sinT = cosT + 1024 * HDIM;
    float* btT  = sinT + 1024 * HDIM;                   // 12*3969 fp32
    unsigned char* maskpad = (unsigned char*)(btT + NHEADS * BT_N);  // 8*1088

    const int nx = MROWS * EMBED / 4;
    const int nw = QKV_N * EMBED / 4;
    const int np = EMBED * EMBED / 4;
    f2bf_kernel<<<(nx + 255) / 256, 256, 0, stream>>>(x, xbf, nx);
    f2bf_kernel<<<(nw + 255) / 256, 256, 0, stream>>>(qkv_w, wbf, nw);
    f2bf_kernel<<<(np + 255) / 256, 256, 0, stream>>>(proj_w, pwbf, np);
    rope_table_kernel<<<1024, 64, 0, stream>>>(cosT, sinT);
    bt_transpose_kernel<<<dim3((BT_N + 255) / 256, NHEADS), 256, 0, stream>>>(rel_bt, btT);
    mask_pad_kernel<<<NBATCH, 256, 0, stream>>>(kmask, maskpad);

    qkv_mfma_kernel<<<dim3((MROWS + 127) / 128, QKV_N / 128), 256, 0, stream>>>(
        xbf, wbf, qkv_b, cosT, sinT, qbuf, kbuf, vbuf);
    attn_mfma_kernel<<<dim3((SEQ + 63) / 64, BHCOUNT), 256, 0, stream>>>(
        qbuf, kbuf, vbuf, btT, maskpad, ctxbf);
    proj_mfma_kernel<<<dim3((MROWS + 127) / 128, EMBED / 128), 256, 0, stream>>>(
        ctxbf, pwbf, proj_b, out);
}